// Round 1
// baseline (2326.874 us; speedup 1.0000x reference)
//
#include <hip/hip_runtime.h>
#include <math.h>

#define NB 4
#define NT 2048
#define ND 1024
#define NH 16
#define NHD 64
#define N3D (3*ND)
#define M1 (NB*NT)   // 8192

// ---------------- GEMM1: qkv = x @ Wqkv, scatter-write into Q/K/V (B,H,T,HD) ----------------
// grid (N3D/64, M1/64), block 256. 64x64 tile, BK=16, 4x4 micro-tile per thread.
__global__ __launch_bounds__(256) void qkv_gemm_kernel(
    const float* __restrict__ X, const float* __restrict__ W,
    float* __restrict__ Qo, float* __restrict__ Ko, float* __restrict__ Vo)
{
    __shared__ float As[16][64];   // [k][m] (transposed store)
    __shared__ float Bs[16][64];   // [k][n]
    const int t  = threadIdx.x;
    const int n0 = blockIdx.x * 64;
    const int m0 = blockIdx.y * 64;
    const int tx = t & 15, ty = t >> 4;
    const int am = t >> 2;            // 0..63
    const int ak = (t & 3) << 2;      // 0,4,8,12
    const int bk = t >> 4;            // 0..15
    const int bn = (t & 15) << 2;     // 0..60

    float acc[4][4] = {};

    for (int k0 = 0; k0 < ND; k0 += 16) {
        const float4 av = *reinterpret_cast<const float4*>(&X[(size_t)(m0 + am) * ND + (k0 + ak)]);
        const float4 bv = *reinterpret_cast<const float4*>(&W[(size_t)(k0 + bk) * N3D + (n0 + bn)]);
        __syncthreads();
        As[ak+0][am] = av.x; As[ak+1][am] = av.y; As[ak+2][am] = av.z; As[ak+3][am] = av.w;
        *reinterpret_cast<float4*>(&Bs[bk][bn]) = bv;
        __syncthreads();
        #pragma unroll
        for (int kk = 0; kk < 16; ++kk) {
            const float4 a4 = *reinterpret_cast<const float4*>(&As[kk][ty << 2]);
            const float4 b4 = *reinterpret_cast<const float4*>(&Bs[kk][tx << 2]);
            const float a[4] = {a4.x, a4.y, a4.z, a4.w};
            const float b[4] = {b4.x, b4.y, b4.z, b4.w};
            #pragma unroll
            for (int i = 0; i < 4; ++i)
                #pragma unroll
                for (int j = 0; j < 4; ++j)
                    acc[i][j] = fmaf(a[i], b[j], acc[i][j]);
        }
    }

    // Scatter epilogue: this block's 64-column span maps to exactly one (s,h).
    const int nb = n0 + (tx << 2);
    const int s  = nb / ND;                  // 0=q,1=k,2=v  (constant per block)
    const int h  = (nb % ND) / NHD;          // constant per block
    const int hd = nb % NHD;                 // = tx*4
    float* dst = (s == 0) ? Qo : (s == 1) ? Ko : Vo;
    #pragma unroll
    for (int i = 0; i < 4; ++i) {
        const int m  = m0 + (ty << 2) + i;
        const int b  = m / NT, tt = m % NT;
        float4 v = make_float4(acc[i][0], acc[i][1], acc[i][2], acc[i][3]);
        *reinterpret_cast<float4*>(&dst[((size_t)(b * NH + h) * NT + tt) * NHD + hd]) = v;
    }
}

// ---------------- GEMM2: out = attn_out @ Wout ----------------
// grid (ND/64, M1/64), block 256.
__global__ __launch_bounds__(256) void out_gemm_kernel(
    const float* __restrict__ A, const float* __restrict__ W, float* __restrict__ C)
{
    __shared__ float As[16][64];
    __shared__ float Bs[16][64];
    const int t  = threadIdx.x;
    const int n0 = blockIdx.x * 64;
    const int m0 = blockIdx.y * 64;
    const int tx = t & 15, ty = t >> 4;
    const int am = t >> 2;
    const int ak = (t & 3) << 2;
    const int bk = t >> 4;
    const int bn = (t & 15) << 2;

    float acc[4][4] = {};

    for (int k0 = 0; k0 < ND; k0 += 16) {
        const float4 av = *reinterpret_cast<const float4*>(&A[(size_t)(m0 + am) * ND + (k0 + ak)]);
        const float4 bv = *reinterpret_cast<const float4*>(&W[(size_t)(k0 + bk) * ND + (n0 + bn)]);
        __syncthreads();
        As[ak+0][am] = av.x; As[ak+1][am] = av.y; As[ak+2][am] = av.z; As[ak+3][am] = av.w;
        *reinterpret_cast<float4*>(&Bs[bk][bn]) = bv;
        __syncthreads();
        #pragma unroll
        for (int kk = 0; kk < 16; ++kk) {
            const float4 a4 = *reinterpret_cast<const float4*>(&As[kk][ty << 2]);
            const float4 b4 = *reinterpret_cast<const float4*>(&Bs[kk][tx << 2]);
            const float a[4] = {a4.x, a4.y, a4.z, a4.w};
            const float b[4] = {b4.x, b4.y, b4.z, b4.w};
            #pragma unroll
            for (int i = 0; i < 4; ++i)
                #pragma unroll
                for (int j = 0; j < 4; ++j)
                    acc[i][j] = fmaf(a[i], b[j], acc[i][j]);
        }
    }

    #pragma unroll
    for (int i = 0; i < 4; ++i) {
        const int m = m0 + (ty << 2) + i;
        float4 v = make_float4(acc[i][0], acc[i][1], acc[i][2], acc[i][3]);
        *reinterpret_cast<float4*>(&C[(size_t)m * ND + n0 + (tx << 2)]) = v;
    }
}

// ---------------- Attention: flash-style, 1 thread = 1 query row ----------------
// grid (NB*NH*(NT/256)), block 256. K/V tiles of 16 rows staged in LDS.
// Mask: attend where pos_i >= pos_j. positions sorted ascending per batch =>
// attended set is a prefix; early-exit when tile-start pos exceeds block max pos.
__global__ __launch_bounds__(256) void attn_kernel(
    const float* __restrict__ Q, const float* __restrict__ K, const float* __restrict__ V,
    const int* __restrict__ pos, float* __restrict__ O)
{
    __shared__ float Ks[16][64];
    __shared__ float Vs[16][64];
    __shared__ int   ps[16];

    const int tid = threadIdx.x;
    const int rb  = blockIdx.x & (NT/256 - 1);  // row tile 0..7
    const int bh  = blockIdx.x >> 3;            // 0..63
    const int b   = bh / NH;
    const int h   = bh % NH;
    const int i   = rb * 256 + tid;             // query row
    const size_t kbase = (size_t)bh * NT;

    // q row into registers
    float q[64];
    {
        const float* qrow = &Q[(kbase + i) * NHD];
        #pragma unroll
        for (int d4 = 0; d4 < 16; ++d4) {
            const float4 v = *reinterpret_cast<const float4*>(&qrow[d4 * 4]);
            q[d4*4+0] = v.x; q[d4*4+1] = v.y; q[d4*4+2] = v.z; q[d4*4+3] = v.w;
        }
    }
    const int pos_i     = pos[b * NT + i];
    const int block_max = pos[b * NT + rb * 256 + 255];  // sorted => last row has max
    const float scale   = 0.125f;                        // 1/sqrt(64)

    float m = -INFINITY, l = 0.f;
    float o[64] = {};

    for (int j0 = 0; j0 < NT; j0 += 16) {
        if (pos[b * NT + j0] > block_max) break;   // uniform: rest fully masked
        __syncthreads();
        {
            const int r = tid >> 4, c = (tid & 15) << 2;
            *reinterpret_cast<float4*>(&Ks[r][c]) =
                *reinterpret_cast<const float4*>(&K[(kbase + j0 + r) * NHD + c]);
            *reinterpret_cast<float4*>(&Vs[r][c]) =
                *reinterpret_cast<const float4*>(&V[(kbase + j0 + r) * NHD + c]);
            if (tid < 16) ps[tid] = pos[b * NT + j0 + tid];
        }
        __syncthreads();

        float s[16];
        #pragma unroll
        for (int jj = 0; jj < 16; ++jj) {
            float acc = 0.f;
            #pragma unroll
            for (int d4 = 0; d4 < 16; ++d4) {
                const float4 kv = *reinterpret_cast<const float4*>(&Ks[jj][d4 * 4]);
                acc = fmaf(q[d4*4+0], kv.x, acc);
                acc = fmaf(q[d4*4+1], kv.y, acc);
                acc = fmaf(q[d4*4+2], kv.z, acc);
                acc = fmaf(q[d4*4+3], kv.w, acc);
            }
            s[jj] = (ps[jj] > pos_i) ? -INFINITY : acc * scale;
        }

        float mnew = m;
        #pragma unroll
        for (int jj = 0; jj < 16; ++jj) mnew = fmaxf(mnew, s[jj]);

        const float factor = __expf(m - mnew);   // m=-inf first tile -> 0 (mnew finite: j=0 unmasked)
        float p[16], psum = 0.f;
        #pragma unroll
        for (int jj = 0; jj < 16; ++jj) { p[jj] = __expf(s[jj] - mnew); psum += p[jj]; }
        l = l * factor + psum;

        #pragma unroll
        for (int d = 0; d < 64; ++d) o[d] *= factor;
        #pragma unroll
        for (int jj = 0; jj < 16; ++jj) {
            #pragma unroll
            for (int d4 = 0; d4 < 16; ++d4) {
                const float4 vv = *reinterpret_cast<const float4*>(&Vs[jj][d4 * 4]);
                o[d4*4+0] = fmaf(p[jj], vv.x, o[d4*4+0]);
                o[d4*4+1] = fmaf(p[jj], vv.y, o[d4*4+1]);
                o[d4*4+2] = fmaf(p[jj], vv.z, o[d4*4+2]);
                o[d4*4+3] = fmaf(p[jj], vv.w, o[d4*4+3]);
            }
        }
        m = mnew;
    }

    const float inv = 1.0f / l;
    float* orow = &O[((size_t)(b * NT + i)) * ND + h * NHD];
    #pragma unroll
    for (int d4 = 0; d4 < 16; ++d4) {
        float4 v = make_float4(o[d4*4+0]*inv, o[d4*4+1]*inv, o[d4*4+2]*inv, o[d4*4+3]*inv);
        *reinterpret_cast<float4*>(&orow[d4 * 4]) = v;
    }
}

extern "C" void kernel_launch(void* const* d_in, const int* in_sizes, int n_in,
                              void* d_out, int out_size, void* d_ws, size_t ws_size,
                              hipStream_t stream) {
    (void)in_sizes; (void)n_in; (void)out_size; (void)ws_size;
    const float* x    = (const float*)d_in[0];
    const int*   pos  = (const int*)d_in[1];
    const float* Wqkv = (const float*)d_in[2];
    const float* Wout = (const float*)d_in[3];
    float* out = (float*)d_out;

    float* ws = (float*)d_ws;
    const size_t NTOK = (size_t)M1;       // 8192 tokens
    float* Qb = ws;                       // (B,H,T,HD)
    float* Kb = Qb + NTOK * ND;
    float* Vb = Kb + NTOK * ND;
    float* AO = Vb + NTOK * ND;           // (B,T,D)

    qkv_gemm_kernel<<<dim3(N3D/64, M1/64), dim3(256), 0, stream>>>(x, Wqkv, Qb, Kb, Vb);
    attn_kernel<<<dim3(NB*NH*(NT/256)), dim3(256), 0, stream>>>(Qb, Kb, Vb, pos, AO);
    out_gemm_kernel<<<dim3(ND/64, M1/64), dim3(256), 0, stream>>>(AO, Wout, out);
}

// Round 2
// 992.825 us; speedup vs baseline: 2.3437x; 2.3437x over previous
//
#include <hip/hip_runtime.h>
#include <math.h>

#define NB 4
#define NT 2048
#define ND 1024
#define NH 16
#define NHD 64
#define N3D 3072
#define M1 8192

typedef __attribute__((ext_vector_type(8))) short bf16x8;
typedef __attribute__((ext_vector_type(4))) float f32x4;
typedef unsigned short u16;
typedef unsigned int u32;

__device__ __forceinline__ u32 bf16rn(float f) {
    u32 u = __float_as_uint(f);
    return (u + 0x7FFFu + ((u >> 16) & 1u)) >> 16;
}
__device__ __forceinline__ u32 pack2(float a, float b) {
    return bf16rn(a) | (bf16rn(b) << 16);
}

// ---------- convert x fp32 -> bf16 (row-major, no transpose) ----------
__global__ __launch_bounds__(256) void convx_kernel(const float* __restrict__ in, u16* __restrict__ out) {
    const int idx = blockIdx.x * 256 + threadIdx.x;   // x4 floats
    const float4 v = *reinterpret_cast<const float4*>(in + (size_t)idx * 4);
    u32 lo = pack2(v.x, v.y), hi = pack2(v.z, v.w);
    *reinterpret_cast<uint2*>(out + (size_t)idx * 4) = make_uint2(lo, hi);
}

// ---------- transpose + convert: in fp32 [R][C] -> out bf16 [C][R] ----------
__global__ __launch_bounds__(256) void tconv_kernel(const float* __restrict__ in, u16* __restrict__ out,
                                                    int R, int C) {
    __shared__ float t[32][33];
    const int bx = blockIdx.x * 32;  // col chunk
    const int by = blockIdx.y * 32;  // row chunk
    const int x = threadIdx.x, y0 = threadIdx.y;
    #pragma unroll
    for (int yy = y0; yy < 32; yy += 8)
        t[yy][x] = in[(size_t)(by + yy) * C + bx + x];
    __syncthreads();
    #pragma unroll
    for (int yy = y0; yy < 32; yy += 8)
        out[(size_t)(bx + yy) * R + by + x] = (u16)bf16rn(t[x][yy]);
}

// ---------- bf16 MFMA GEMM core: A[M][1024] bf16, Bt[N][1024] bf16 ----------
// 128x128 tile, BK=32, 4 waves (2x2 of 64x64), XOR-swizzled LDS.
#define GEMM_PROLOGUE(Aptr, Btptr)                                                            \
    __shared__ __align__(16) u16 As[4096];                                                    \
    __shared__ __align__(16) u16 Bs[4096];                                                    \
    const int tid = threadIdx.x;                                                              \
    const int lane = tid & 63, wave = tid >> 6;                                               \
    const int wr = wave >> 1, wc = wave & 1;                                                  \
    const int n0 = blockIdx.x * 128, m0 = blockIdx.y * 128;                                   \
    const int c0 = tid, c1 = tid + 256;                                                       \
    const int pA0 = (c0 * 16) ^ ((((c0 * 16) >> 6) & 7) << 4);                                \
    const int pA1 = (c1 * 16) ^ ((((c1 * 16) >> 6) & 7) << 4);                                \
    const u16* gA0 = Aptr + (size_t)(m0 + (c0 >> 2)) * 1024 + (c0 & 3) * 8;                   \
    const u16* gA1 = Aptr + (size_t)(m0 + (c1 >> 2)) * 1024 + (c1 & 3) * 8;                   \
    const u16* gB0 = Btptr + (size_t)(n0 + (c0 >> 2)) * 1024 + (c0 & 3) * 8;                  \
    const u16* gB1 = Btptr + (size_t)(n0 + (c1 >> 2)) * 1024 + (c1 & 3) * 8;                  \
    int offA[4], offB[4];                                                                     \
    {                                                                                         \
        const int kb = (lane >> 4) * 16;                                                      \
        _Pragma("unroll")                                                                     \
        for (int mm = 0; mm < 4; ++mm) {                                                      \
            int row = wr * 64 + mm * 16 + (lane & 15);                                        \
            offA[mm] = (row * 64 + kb) ^ ((row & 7) << 4);                                    \
        }                                                                                     \
        _Pragma("unroll")                                                                     \
        for (int nn = 0; nn < 4; ++nn) {                                                      \
            int row = wc * 64 + nn * 16 + (lane & 15);                                        \
            offB[nn] = (row * 64 + kb) ^ ((row & 7) << 4);                                    \
        }                                                                                     \
    }                                                                                         \
    f32x4 acc[4][4];                                                                          \
    _Pragma("unroll")                                                                         \
    for (int mm = 0; mm < 4; ++mm)                                                            \
        _Pragma("unroll")                                                                     \
        for (int nn = 0; nn < 4; ++nn)                                                        \
            acc[mm][nn] = (f32x4){0.f, 0.f, 0.f, 0.f};                                        \
    uint4 va0 = *(const uint4*)gA0, va1 = *(const uint4*)gA1;                                 \
    uint4 vb0 = *(const uint4*)gB0, vb1 = *(const uint4*)gB1;                                 \
    for (int k0 = 0; k0 < 1024; k0 += 32) {                                                   \
        __syncthreads();                                                                      \
        *(uint4*)((char*)As + pA0) = va0;                                                     \
        *(uint4*)((char*)As + pA1) = va1;                                                     \
        *(uint4*)((char*)Bs + pB(0)) = vb0;                                                   \
        *(uint4*)((char*)Bs + pB(1)) = vb1;                                                   \
        __syncthreads();                                                                      \
        if (k0 + 32 < 1024) {                                                                 \
            gA0 += 32; gA1 += 32; gB0 += 32; gB1 += 32;                                       \
            va0 = *(const uint4*)gA0; va1 = *(const uint4*)gA1;                               \
            vb0 = *(const uint4*)gB0; vb1 = *(const uint4*)gB1;                               \
        }                                                                                     \
        bf16x8 aF[4], bF[4];                                                                  \
        _Pragma("unroll")                                                                     \
        for (int mm = 0; mm < 4; ++mm) aF[mm] = *(const bf16x8*)((const char*)As + offA[mm]); \
        _Pragma("unroll")                                                                     \
        for (int nn = 0; nn < 4; ++nn) bF[nn] = *(const bf16x8*)((const char*)Bs + offB[nn]); \
        _Pragma("unroll")                                                                     \
        for (int mm = 0; mm < 4; ++mm)                                                        \
            _Pragma("unroll")                                                                 \
            for (int nn = 0; nn < 4; ++nn)                                                    \
                acc[mm][nn] = __builtin_amdgcn_mfma_f32_16x16x32_bf16(aF[mm], bF[nn],         \
                                                                      acc[mm][nn], 0, 0, 0); \
    }
#define pB(r) ((r) ? pA1 : pA0)

// qkv GEMM: C column n -> (s,h,hd) scatter into Q/K/V (B,H,T,HD) fp32
__global__ __launch_bounds__(256) void gemm_qkv_kernel(
    const u16* __restrict__ A, const u16* __restrict__ Bt,
    float* __restrict__ Qo, float* __restrict__ Ko, float* __restrict__ Vo)
{
    GEMM_PROLOGUE(A, Bt)
    const int nbase = n0 + wc * 64;
    #pragma unroll
    for (int nn = 0; nn < 4; ++nn) {
        const int n_abs = nbase + nn * 16 + (lane & 15);
        const int s  = n_abs >> 10;
        const int hh = (n_abs >> 6) & 15;
        const int hd = n_abs & 63;
        float* dst = (s == 0) ? Qo : (s == 1) ? Ko : Vo;
        #pragma unroll
        for (int mm = 0; mm < 4; ++mm) {
            const int rbase = m0 + wr * 64 + mm * 16 + ((lane >> 4) << 2);
            #pragma unroll
            for (int r = 0; r < 4; ++r) {
                const int row = rbase + r;
                const int b = row >> 11, t = row & 2047;
                dst[((size_t)((b << 4) + hh) * 2048 + t) * 64 + hd] = acc[mm][nn][r];
            }
        }
    }
}

// out GEMM: plain row-major fp32 C [M][1024]
__global__ __launch_bounds__(256) void gemm_out_kernel(
    const u16* __restrict__ A, const u16* __restrict__ Bt, float* __restrict__ C)
{
    GEMM_PROLOGUE(A, Bt)
    const int nbase = n0 + wc * 64;
    #pragma unroll
    for (int nn = 0; nn < 4; ++nn) {
        const int n_abs = nbase + nn * 16 + (lane & 15);
        #pragma unroll
        for (int mm = 0; mm < 4; ++mm) {
            const int rbase = m0 + wr * 64 + mm * 16 + ((lane >> 4) << 2);
            #pragma unroll
            for (int r = 0; r < 4; ++r)
                C[(size_t)(rbase + r) * 1024 + n_abs] = acc[mm][nn][r];
        }
    }
}

// ---------- attention: 4 threads per query row, flash-style ----------
// block 256 = 64 rows x 4 subs; each sub owns 16 of 64 dims.
__global__ __launch_bounds__(256) void attn2_kernel(
    const float* __restrict__ Q, const float* __restrict__ K, const float* __restrict__ V,
    const int* __restrict__ pos, u16* __restrict__ AO)
{
    __shared__ float Ks[16][68];
    __shared__ float Vs[16][68];
    __shared__ int ps[16];

    const int tid = threadIdx.x;
    const int bh = blockIdx.x & 63;
    const int rb = 31 - (blockIdx.x >> 6);   // longest-prefix blocks first
    const int b = bh >> 4, h = bh & 15;
    const int rl = tid >> 2, sub = tid & 3;
    const int i = rb * 64 + rl;
    const size_t base = (size_t)bh * 2048;

    float q[16];
    {
        const float* qrow = &Q[(base + i) * 64 + sub * 16];
        #pragma unroll
        for (int d4 = 0; d4 < 4; ++d4) {
            const float4 v = *reinterpret_cast<const float4*>(qrow + d4 * 4);
            q[d4*4+0] = v.x; q[d4*4+1] = v.y; q[d4*4+2] = v.z; q[d4*4+3] = v.w;
        }
    }
    const int pos_i = pos[b * 2048 + i];
    const int bmax  = pos[b * 2048 + rb * 64 + 63];

    float m = -INFINITY, l = 0.f;
    float o[16];
    #pragma unroll
    for (int d = 0; d < 16; ++d) o[d] = 0.f;

    for (int j0 = 0; j0 < 2048; j0 += 16) {
        if (pos[b * 2048 + j0] > bmax) break;
        __syncthreads();
        {
            const int r = tid >> 4, c = (tid & 15) * 4;
            *reinterpret_cast<float4*>(&Ks[r][c]) =
                *reinterpret_cast<const float4*>(&K[(base + j0 + r) * 64 + c]);
            *reinterpret_cast<float4*>(&Vs[r][c]) =
                *reinterpret_cast<const float4*>(&V[(base + j0 + r) * 64 + c]);
            if (tid < 16) ps[tid] = pos[b * 2048 + j0 + tid];
        }
        __syncthreads();

        float s[16];
        #pragma unroll
        for (int jj = 0; jj < 16; ++jj) {
            float a = 0.f;
            #pragma unroll
            for (int d4 = 0; d4 < 4; ++d4) {
                const float4 kv = *reinterpret_cast<const float4*>(&Ks[jj][sub * 16 + d4 * 4]);
                a = fmaf(q[d4*4+0], kv.x, a);
                a = fmaf(q[d4*4+1], kv.y, a);
                a = fmaf(q[d4*4+2], kv.z, a);
                a = fmaf(q[d4*4+3], kv.w, a);
            }
            s[jj] = a;
        }
        #pragma unroll
        for (int jj = 0; jj < 16; ++jj) {
            s[jj] += __shfl_xor(s[jj], 1);
            s[jj] += __shfl_xor(s[jj], 2);
            s[jj] = (ps[jj] > pos_i) ? -INFINITY : s[jj] * 0.125f;
        }

        float mnew = m;
        #pragma unroll
        for (int jj = 0; jj < 16; ++jj) mnew = fmaxf(mnew, s[jj]);

        const float factor = __expf(m - mnew);
        float p[16], psum = 0.f;
        #pragma unroll
        for (int jj = 0; jj < 16; ++jj) { p[jj] = __expf(s[jj] - mnew); psum += p[jj]; }
        l = l * factor + psum;

        #pragma unroll
        for (int d = 0; d < 16; ++d) o[d] *= factor;
        #pragma unroll
        for (int jj = 0; jj < 16; ++jj) {
            const float pj = p[jj];
            #pragma unroll
            for (int d4 = 0; d4 < 4; ++d4) {
                const float4 vv = *reinterpret_cast<const float4*>(&Vs[jj][sub * 16 + d4 * 4]);
                o[d4*4+0] = fmaf(pj, vv.x, o[d4*4+0]);
                o[d4*4+1] = fmaf(pj, vv.y, o[d4*4+1]);
                o[d4*4+2] = fmaf(pj, vv.z, o[d4*4+2]);
                o[d4*4+3] = fmaf(pj, vv.w, o[d4*4+3]);
            }
        }
        m = mnew;
    }

    const float inv = 1.f / l;
    u32 w[8];
    #pragma unroll
    for (int d2 = 0; d2 < 8; ++d2) w[d2] = pack2(o[d2*2] * inv, o[d2*2+1] * inv);
    u16* dst = AO + ((size_t)(b * 2048 + i) * 1024 + h * 64 + sub * 16);
    *reinterpret_cast<uint4*>(dst)     = make_uint4(w[0], w[1], w[2], w[3]);
    *reinterpret_cast<uint4*>(dst + 8) = make_uint4(w[4], w[5], w[6], w[7]);
}

extern "C" void kernel_launch(void* const* d_in, const int* in_sizes, int n_in,
                              void* d_out, int out_size, void* d_ws, size_t ws_size,
                              hipStream_t stream) {
    (void)in_sizes; (void)n_in; (void)out_size; (void)ws_size;
    const float* x    = (const float*)d_in[0];
    const int*   pos  = (const int*)d_in[1];
    const float* Wqkv = (const float*)d_in[2];
    const float* Wout = (const float*)d_in[3];
    float* out = (float*)d_out;

    char* ws = (char*)d_ws;
    u16*   xb     = (u16*)(ws);                       // 16,777,216 B  (also AO later)
    u16*   WqkvT  = (u16*)(ws + 16777216);            //  6,291,456 B
    u16*   WoutT  = (u16*)(ws + 23068672);            //  2,097,152 B
    float* Qb     = (float*)(ws + 25165824);          // 33,554,432 B
    float* Kb     = (float*)(ws + 58720256);
    float* Vb     = (float*)(ws + 92274688);
    u16*   AO     = xb;                                // alias: xb dead after gemm1

    convx_kernel<<<dim3(M1 * ND / (256 * 4)), dim3(256), 0, stream>>>(x, xb);
    tconv_kernel<<<dim3(N3D / 32, ND / 32), dim3(32, 8), 0, stream>>>(Wqkv, WqkvT, ND, N3D);
    tconv_kernel<<<dim3(ND / 32, ND / 32), dim3(32, 8), 0, stream>>>(Wout, WoutT, ND, ND);
    gemm_qkv_kernel<<<dim3(N3D / 128, M1 / 128), dim3(256), 0, stream>>>(xb, WqkvT, Qb, Kb, Vb);
    attn2_kernel<<<dim3(64 * (NT / 64)), dim3(256), 0, stream>>>(Qb, Kb, Vb, pos, AO);
    gemm_out_kernel<<<dim3(ND / 128, M1 / 128), dim3(256), 0, stream>>>(AO, WoutT, out);
}

// Round 4
// 385.579 us; speedup vs baseline: 6.0348x; 2.5749x over previous
//
#include <hip/hip_runtime.h>
#include <math.h>

#define NB 4
#define NT 2048
#define ND 1024
#define NH 16
#define NHD 64
#define N3D 3072
#define M1 8192

typedef __attribute__((ext_vector_type(8))) short bf16x8;
typedef __attribute__((ext_vector_type(4))) float f32x4;
typedef __attribute__((ext_vector_type(4))) unsigned int u32x4;
typedef unsigned short u16;
typedef unsigned int u32;

__device__ __forceinline__ u32 bf16rn(float f) {
    u32 u = __float_as_uint(f);
    return (u + 0x7FFFu + ((u >> 16) & 1u)) >> 16;
}
__device__ __forceinline__ u32 pack2(float a, float b) {
    return bf16rn(a) | (bf16rn(b) << 16);
}
__device__ __forceinline__ u32 cvtpk(float lo, float hi) {
    u32 r;
    asm("v_cvt_pk_bf16_f32 %0, %1, %2" : "=v"(r) : "v"(lo), "v"(hi));
    return r;
}

// ---------- convert x fp32 -> bf16 ----------
__global__ __launch_bounds__(256) void convx_kernel(const float* __restrict__ in, u16* __restrict__ out) {
    const int idx = blockIdx.x * 256 + threadIdx.x;
    const float4 v = *reinterpret_cast<const float4*>(in + (size_t)idx * 4);
    *reinterpret_cast<uint2*>(out + (size_t)idx * 4) = make_uint2(pack2(v.x, v.y), pack2(v.z, v.w));
}

// ---------- transpose + convert: fp32 [R][C] -> bf16 [C][R] ----------
__global__ __launch_bounds__(256) void tconv_kernel(const float* __restrict__ in, u16* __restrict__ out,
                                                    int R, int C) {
    __shared__ float t[32][33];
    const int bx = blockIdx.x * 32, by = blockIdx.y * 32;
    const int x = threadIdx.x, y0 = threadIdx.y;
    #pragma unroll
    for (int yy = y0; yy < 32; yy += 8) t[yy][x] = in[(size_t)(by + yy) * C + bx + x];
    __syncthreads();
    #pragma unroll
    for (int yy = y0; yy < 32; yy += 8) out[(size_t)(bx + yy) * R + by + x] = (u16)bf16rn(t[x][yy]);
}

// ---------- bf16 MFMA GEMM core (128x128 tile, BK=32, 4 waves) ----------
#define GEMM_PROLOGUE(Aptr, Btptr)                                                            \
    __shared__ __align__(16) u16 As[4096];                                                    \
    __shared__ __align__(16) u16 Bs[4096];                                                    \
    const int tid = threadIdx.x;                                                              \
    const int lane = tid & 63, wave = tid >> 6;                                               \
    const int wr = wave >> 1, wc = wave & 1;                                                  \
    const int n0 = blockIdx.x * 128, m0 = blockIdx.y * 128;                                   \
    const int c0 = tid, c1 = tid + 256;                                                       \
    const int pA0 = (c0 * 16) ^ ((((c0 * 16) >> 6) & 7) << 4);                                \
    const int pA1 = (c1 * 16) ^ ((((c1 * 16) >> 6) & 7) << 4);                                \
    const u16* gA0 = Aptr + (size_t)(m0 + (c0 >> 2)) * 1024 + (c0 & 3) * 8;                   \
    const u16* gA1 = Aptr + (size_t)(m0 + (c1 >> 2)) * 1024 + (c1 & 3) * 8;                   \
    const u16* gB0 = Btptr + (size_t)(n0 + (c0 >> 2)) * 1024 + (c0 & 3) * 8;                  \
    const u16* gB1 = Btptr + (size_t)(n0 + (c1 >> 2)) * 1024 + (c1 & 3) * 8;                  \
    int offA[4], offB[4];                                                                     \
    {                                                                                         \
        const int kb = (lane >> 4) * 16;                                                      \
        _Pragma("unroll")                                                                     \
        for (int mm = 0; mm < 4; ++mm) {                                                      \
            int row = wr * 64 + mm * 16 + (lane & 15);                                        \
            offA[mm] = (row * 64 + kb) ^ ((row & 7) << 4);                                    \
        }                                                                                     \
        _Pragma("unroll")                                                                     \
        for (int nn = 0; nn < 4; ++nn) {                                                      \
            int row = wc * 64 + nn * 16 + (lane & 15);                                        \
            offB[nn] = (row * 64 + kb) ^ ((row & 7) << 4);                                    \
        }                                                                                     \
    }                                                                                         \
    f32x4 acc[4][4];                                                                          \
    _Pragma("unroll")                                                                         \
    for (int mm = 0; mm < 4; ++mm)                                                            \
        _Pragma("unroll")                                                                     \
        for (int nn = 0; nn < 4; ++nn)                                                        \
            acc[mm][nn] = (f32x4){0.f, 0.f, 0.f, 0.f};                                        \
    uint4 va0 = *(const uint4*)gA0, va1 = *(const uint4*)gA1;                                 \
    uint4 vb0 = *(const uint4*)gB0, vb1 = *(const uint4*)gB1;                                 \
    for (int k0 = 0; k0 < 1024; k0 += 32) {                                                   \
        __syncthreads();                                                                      \
        *(uint4*)((char*)As + pA0) = va0;                                                     \
        *(uint4*)((char*)As + pA1) = va1;                                                     \
        *(uint4*)((char*)Bs + pA0) = vb0;                                                     \
        *(uint4*)((char*)Bs + pA1) = vb1;                                                     \
        __syncthreads();                                                                      \
        if (k0 + 32 < 1024) {                                                                 \
            gA0 += 32; gA1 += 32; gB0 += 32; gB1 += 32;                                       \
            va0 = *(const uint4*)gA0; va1 = *(const uint4*)gA1;                               \
            vb0 = *(const uint4*)gB0; vb1 = *(const uint4*)gB1;                               \
        }                                                                                     \
        bf16x8 aF[4], bF[4];                                                                  \
        _Pragma("unroll")                                                                     \
        for (int mm = 0; mm < 4; ++mm) aF[mm] = *(const bf16x8*)((const char*)As + offA[mm]); \
        _Pragma("unroll")                                                                     \
        for (int nn = 0; nn < 4; ++nn) bF[nn] = *(const bf16x8*)((const char*)Bs + offB[nn]); \
        _Pragma("unroll")                                                                     \
        for (int mm = 0; mm < 4; ++mm)                                                        \
            _Pragma("unroll")                                                                 \
            for (int nn = 0; nn < 4; ++nn)                                                    \
                acc[mm][nn] = __builtin_amdgcn_mfma_f32_16x16x32_bf16(aF[mm], bF[nn],         \
                                                                      acc[mm][nn], 0, 0, 0); \
    }

// qkv GEMM: write bf16 Q (pre-scaled), bf16 K [bh][t][d], bf16 V transposed [bh][d][t]
__global__ __launch_bounds__(256) void gemm_qkv_kernel(
    const u16* __restrict__ A, const u16* __restrict__ Bt,
    u16* __restrict__ Qo, u16* __restrict__ Ko, u16* __restrict__ Vo)
{
    GEMM_PROLOGUE(A, Bt)
    const float qsc = 0.18033688011112042f;  // 0.125 * log2(e)
    const int nbase = n0 + wc * 64;
    #pragma unroll
    for (int nn = 0; nn < 4; ++nn) {
        const int n_abs = nbase + nn * 16 + (lane & 15);
        const int s  = n_abs >> 10;
        const int hh = (n_abs >> 6) & 15;
        const int hd = n_abs & 63;
        #pragma unroll
        for (int mm = 0; mm < 4; ++mm) {
            const int rbase = m0 + wr * 64 + mm * 16 + ((lane >> 4) << 2);
            const int b = rbase >> 11, t0 = rbase & 2047;
            const int bh = (b << 4) + hh;
            if (s == 0) {
                #pragma unroll
                for (int r = 0; r < 4; ++r)
                    Qo[((size_t)bh * 2048 + t0 + r) * 64 + hd] = (u16)bf16rn(acc[mm][nn][r] * qsc);
            } else if (s == 1) {
                #pragma unroll
                for (int r = 0; r < 4; ++r)
                    Ko[((size_t)bh * 2048 + t0 + r) * 64 + hd] = (u16)bf16rn(acc[mm][nn][r]);
            } else {
                uint2 w = make_uint2(pack2(acc[mm][nn][0], acc[mm][nn][1]),
                                     pack2(acc[mm][nn][2], acc[mm][nn][3]));
                *reinterpret_cast<uint2*>(&Vo[((size_t)bh * 64 + hd) * 2048 + t0]) = w;
            }
        }
    }
}

// out GEMM: fp32 C row-major
__global__ __launch_bounds__(256) void gemm_out_kernel(
    const u16* __restrict__ A, const u16* __restrict__ Bt, float* __restrict__ C)
{
    GEMM_PROLOGUE(A, Bt)
    const int nbase = n0 + wc * 64;
    #pragma unroll
    for (int nn = 0; nn < 4; ++nn) {
        const int n_abs = nbase + nn * 16 + (lane & 15);
        #pragma unroll
        for (int mm = 0; mm < 4; ++mm) {
            const int rbase = m0 + wr * 64 + mm * 16 + ((lane >> 4) << 2);
            #pragma unroll
            for (int r = 0; r < 4; ++r)
                C[(size_t)(rbase + r) * 1024 + n_abs] = acc[mm][nn][r];
        }
    }
}

// ---------- MFMA flash attention ----------
// grid 1024 (XCD-swizzled), block 256 = 4 waves. Wave owns 32 q rows.
// Swapped QK^T: S^T = mfma(K, Q); lane holds one q-column => softmax lane-local + 2 shfl.
// PV: O^T = mfma(V^T, P^T), P^T fragments via cvt_pk_bf16 + ds_bpermute.
// Prefix mask via exact per-row bound (12-iter binary search over 2049 answers).
__global__ __launch_bounds__(256, 2) void attn3_kernel(
    const u16* __restrict__ Q, const u16* __restrict__ K, const u16* __restrict__ Vt,
    const int* __restrict__ pos, u16* __restrict__ AO)
{
    __shared__ int bndS[128];

    const int wg = ((blockIdx.x & 7) << 7) + (blockIdx.x >> 3);  // bijective XCD swizzle
    const int bh = wg >> 4;
    const int qb = 15 - (wg & 15);
    const int b  = bh >> 4, h = bh & 15;
    const int tid = threadIdx.x, lane = tid & 63, wave = tid >> 6;
    const int g = lane >> 4, col = lane & 15;

    // per-row attended-prefix bound: first index with pos > pos_row (exact: 12 iters)
    if (tid < 128) {
        const int target = pos[b * 2048 + qb * 128 + tid];
        int lo = 0, hi = 2048;
        #pragma unroll
        for (int it = 0; it < 12; ++it) {
            const int mid = (lo + hi) >> 1;
            if (lo < hi) { if (pos[b * 2048 + mid] <= target) lo = mid + 1; else hi = mid; }
        }
        bndS[tid] = lo;
    }
    __syncthreads();

    const int bnd0 = bndS[wave * 32 + col];
    const int bnd1 = bndS[wave * 32 + 16 + col];
    const int bnd_min = bndS[wave * 32];
    const int bnd_max = bndS[wave * 32 + 31];

    // Q fragments (already scaled by 0.125*log2e)
    bf16x8 qf[2][2];
    const int i0 = qb * 128 + wave * 32 + col;
    #pragma unroll
    for (int m = 0; m < 2; ++m)
        #pragma unroll
        for (int kc = 0; kc < 2; ++kc)
            qf[m][kc] = *(const bf16x8*)&Q[((size_t)bh * 2048 + i0 + m * 16) * 64 + kc * 32 + g * 8];

    // bpermute lane indices for the P^T gather
    int idxp[4];
    #pragma unroll
    for (int t = 0; t < 4; ++t) idxp[t] = (col + 16 * (2 * (g & 1) + (t >> 1))) * 4;
    const bool hiHalf = (lane >= 32);

    float mrun[2] = {-INFINITY, -INFINITY};
    float lrun[2] = {0.f, 0.f};
    f32x4 oT[2][4];
    #pragma unroll
    for (int m = 0; m < 2; ++m)
        #pragma unroll
        for (int dt = 0; dt < 4; ++dt) oT[m][dt] = (f32x4){0.f, 0.f, 0.f, 0.f};

    for (int j0 = 0; j0 < bnd_max; j0 += 64) {
        bf16x8 kf[4][2];
        #pragma unroll
        for (int n = 0; n < 4; ++n)
            #pragma unroll
            for (int kc = 0; kc < 2; ++kc)
                kf[n][kc] = *(const bf16x8*)&K[((size_t)bh * 2048 + j0 + 16 * n + col) * 64 + kc * 32 + g * 8];
        bf16x8 vf[4][2];
        #pragma unroll
        for (int dt = 0; dt < 4; ++dt)
            #pragma unroll
            for (int kc = 0; kc < 2; ++kc)
                vf[dt][kc] = *(const bf16x8*)&Vt[((size_t)bh * 64 + dt * 16 + col) * 2048 + j0 + kc * 32 + g * 8];

        // S^T = K · Q^T  (lane: col=q, rows k = 16n + g*4 + r)
        f32x4 st[2][4];
        #pragma unroll
        for (int m = 0; m < 2; ++m)
            #pragma unroll
            for (int n = 0; n < 4; ++n) {
                f32x4 z = (f32x4){0.f, 0.f, 0.f, 0.f};
                z = __builtin_amdgcn_mfma_f32_16x16x32_bf16(kf[n][0], qf[m][0], z, 0, 0, 0);
                st[m][n] = __builtin_amdgcn_mfma_f32_16x16x32_bf16(kf[n][1], qf[m][1], z, 0, 0, 0);
            }

        // mask: k >= bnd(q)
        if (j0 + 64 > bnd_min) {
            #pragma unroll
            for (int m = 0; m < 2; ++m) {
                const int bnd = m ? bnd1 : bnd0;
                #pragma unroll
                for (int n = 0; n < 4; ++n)
                    #pragma unroll
                    for (int r = 0; r < 4; ++r)
                        if (j0 + 16 * n + g * 4 + r >= bnd) st[m][n][r] = -INFINITY;
            }
        }

        #pragma unroll
        for (int m = 0; m < 2; ++m) {
            float rm = st[m][0][0];
            #pragma unroll
            for (int n = 0; n < 4; ++n)
                #pragma unroll
                for (int r = 0; r < 4; ++r) rm = fmaxf(rm, st[m][n][r]);
            rm = fmaxf(rm, __shfl_xor(rm, 16));
            rm = fmaxf(rm, __shfl_xor(rm, 32));
            const float mnew = fmaxf(mrun[m], rm);
            const float factor = __builtin_amdgcn_exp2f(mrun[m] - mnew);
            mrun[m] = mnew;
            float psum = 0.f;
            #pragma unroll
            for (int n = 0; n < 4; ++n)
                #pragma unroll
                for (int r = 0; r < 4; ++r) {
                    const float p = __builtin_amdgcn_exp2f(st[m][n][r] - mnew);
                    st[m][n][r] = p;
                    psum += p;
                }
            psum += __shfl_xor(psum, 16);
            psum += __shfl_xor(psum, 32);
            lrun[m] = lrun[m] * factor + psum;
            #pragma unroll
            for (int dt = 0; dt < 4; ++dt)
                #pragma unroll
                for (int r = 0; r < 4; ++r) oT[m][dt][r] *= factor;
        }

        // pack P to bf16 pairs
        u32 w[2][4][2];
        #pragma unroll
        for (int m = 0; m < 2; ++m)
            #pragma unroll
            for (int n = 0; n < 4; ++n) {
                w[m][n][0] = cvtpk(st[m][n][0], st[m][n][1]);
                w[m][n][1] = cvtpk(st[m][n][2], st[m][n][3]);
            }

        // PV: O^T += V^T · P^T
        #pragma unroll
        for (int m = 0; m < 2; ++m) {
            #pragma unroll
            for (int kc = 0; kc < 2; ++kc) {
                u32x4 pw;
                #pragma unroll
                for (int t = 0; t < 4; ++t) {
                    const int e = t & 1;
                    const u32 loW = (u32)__builtin_amdgcn_ds_bpermute(idxp[t], (int)w[m][2 * kc + 0][e]);
                    const u32 hiW = (u32)__builtin_amdgcn_ds_bpermute(idxp[t], (int)w[m][2 * kc + 1][e]);
                    pw[t] = hiHalf ? hiW : loW;
                }
                union { u32x4 u; bf16x8 bv; } cvt;
                cvt.u = pw;
                const bf16x8 pfrag = cvt.bv;
                #pragma unroll
                for (int dt = 0; dt < 4; ++dt)
                    oT[m][dt] = __builtin_amdgcn_mfma_f32_16x16x32_bf16(vf[dt][kc], pfrag, oT[m][dt], 0, 0, 0);
            }
        }
    }

    // epilogue
    #pragma unroll
    for (int m = 0; m < 2; ++m) {
        const float inv = 1.f / lrun[m];
        const int t = i0 + m * 16;
        #pragma unroll
        for (int dt = 0; dt < 4; ++dt) {
            uint2 wv = make_uint2(pack2(oT[m][dt][0] * inv, oT[m][dt][1] * inv),
                                  pack2(oT[m][dt][2] * inv, oT[m][dt][3] * inv));
            *reinterpret_cast<uint2*>(&AO[((size_t)(b * 2048 + t)) * 1024 + h * 64 + dt * 16 + g * 4]) = wv;
        }
    }
}

extern "C" void kernel_launch(void* const* d_in, const int* in_sizes, int n_in,
                              void* d_out, int out_size, void* d_ws, size_t ws_size,
                              hipStream_t stream) {
    (void)in_sizes; (void)n_in; (void)out_size; (void)ws_size;
    const float* x    = (const float*)d_in[0];
    const int*   pos  = (const int*)d_in[1];
    const float* Wqkv = (const float*)d_in[2];
    const float* Wout = (const float*)d_in[3];
    float* out = (float*)d_out;

    char* ws = (char*)d_ws;
    u16* xb    = (u16*)(ws);                 // 16 MB (aliased as AO after gemm1 consumes it)
    u16* WqkvT = (u16*)(ws + 16777216);      // 6 MB
    u16* WoutT = (u16*)(ws + 23068672);      // 2 MB
    u16* Qb    = (u16*)(ws + 25165824);      // 16 MB bf16 [bh][t][d], pre-scaled
    u16* Kb    = (u16*)(ws + 41943040);      // 16 MB bf16 [bh][t][d]
    u16* Vtb   = (u16*)(ws + 58720256);      // 16 MB bf16 [bh][d][t]
    u16* AO    = xb;

    convx_kernel<<<dim3(M1 * ND / (256 * 4)), dim3(256), 0, stream>>>(x, xb);
    tconv_kernel<<<dim3(N3D / 32, ND / 32), dim3(32, 8), 0, stream>>>(Wqkv, WqkvT, ND, N3D);
    tconv_kernel<<<dim3(ND / 32, ND / 32), dim3(32, 8), 0, stream>>>(Wout, WoutT, ND, ND);
    gemm_qkv_kernel<<<dim3(N3D / 128, M1 / 128), dim3(256), 0, stream>>>(xb, WqkvT, Qb, Kb, Vtb);
    attn3_kernel<<<dim3(1024), dim3(256), 0, stream>>>(Qb, Kb, Vtb, pos, AO);
    gemm_out_kernel<<<dim3(ND / 128, M1 / 128), dim3(256), 0, stream>>>(AO, WoutT, out);
}